// Round 6
// baseline (135.955 us; speedup 1.0000x reference)
//
#include <hip/hip_runtime.h>
#include <hip/hip_bf16.h>

typedef __bf16 bf16;
typedef __attribute__((ext_vector_type(8))) __bf16 bf16x8;
typedef __attribute__((ext_vector_type(4))) __bf16 bf16x4;
typedef __attribute__((ext_vector_type(4))) float f32x4;

#define NB 2
#define NC 2048
#define NM 1024
#define NH 16
#define NK 64
#define NV 64
#define NHV 1024   // NH*NV

#define MFMA(a, b, c) __builtin_amdgcn_mfma_f32_16x16x32_bf16((a), (b), (c), 0, 0, 0)

// ---------------- fused prep kernel ----------------
__global__ __launch_bounds__(256) void prep_kernel(
    const float* __restrict__ qin, const float* __restrict__ kvin,
    const float* __restrict__ wq, const float* __restrict__ wk,
    const float* __restrict__ wv, const float* __restrict__ wo,
    bf16* __restrict__ qb, bf16* __restrict__ kvb,
    bf16* __restrict__ wqT, bf16* __restrict__ wkT,
    bf16* __restrict__ wvT, bf16* __restrict__ woT) {
  __shared__ float tile[32][33];
  const int bx = blockIdx.x;
  const int tid = threadIdx.x;
  if (bx < 1024) {
    const float4* src = (const float4*)((bx < 512) ? qin : kvin);
    bf16x4* dst = (bf16x4*)((bx < 512) ? qb : kvb);
    int base = (bx & 511) * 2048;
#pragma unroll
    for (int k = 0; k < 8; ++k) {
      int i = base + k * 256 + tid;
      float4 v = src[i];
      bf16x4 o;
      o.x = (bf16)v.x; o.y = (bf16)v.y; o.z = (bf16)v.z; o.w = (bf16)v.w;
      dst[i] = o;
    }
  } else if (bx < 4096) {
    const int sel = (bx >> 10) - 1;  // 0=wq 1=wk 2=wv
    const float* w = (sel == 0) ? wq : (sel == 1) ? wk : wv;
    bf16* wT = (sel == 0) ? wqT : (sel == 1) ? wkT : wvT;
    const int t = bx & 1023;
    const int k0 = (t & 1) * 32, m0 = ((t >> 1) & 31) * 32, h = t >> 6;
    const int tx = tid & 31, ty = tid >> 5;  // 32 x 8
#pragma unroll
    for (int dy = 0; dy < 32; dy += 8)
      tile[ty + dy][tx] = w[((size_t)h * NM + m0 + ty + dy) * NK + k0 + tx];
    __syncthreads();
#pragma unroll
    for (int dy = 0; dy < 32; dy += 8)
      wT[((size_t)h * NK + k0 + ty + dy) * NM + m0 + tx] = (bf16)tile[tx][ty + dy];
  } else {
    const int t = bx & 1023;
    const int hv0 = (t & 31) * 32, m0 = (t >> 5) * 32;
    const int tx = tid & 31, ty = tid >> 5;
#pragma unroll
    for (int dy = 0; dy < 32; dy += 8)
      tile[ty + dy][tx] = wo[((size_t)(hv0 + ty + dy)) * NM + m0 + tx];
    __syncthreads();
#pragma unroll
    for (int dy = 0; dy < 32; dy += 8)
      woT[((size_t)(m0 + ty + dy)) * NHV + hv0 + tx] = (bf16)tile[tx][ty + dy];
  }
}

// ---------------- tiled GEMM core (128x128 tile, BK=64, m97-style) ----------------

#define GEMM_BODY(Aptr, BTptr)                                                     \
  __shared__ bf16 Al[128 * 64], Bl[128 * 64];                                      \
  const int m0 = blockIdx.x * 128, n0 = blockIdx.y * 128;                          \
  const int tid = threadIdx.x;                                                     \
  const int w = tid >> 6, lane = tid & 63, lr = lane & 15, lg = lane >> 4;         \
  const int wm = w >> 1, wn = w & 1;                                               \
  f32x4 acc[4][4] = {};                                                            \
  for (int k0 = 0; k0 < 1024; k0 += 64) {                                          \
    _Pragma("unroll")                                                              \
    for (int it = 0; it < 4; ++it) {                                               \
      int id = it * 256 + tid;                                                     \
      int row = id >> 3, ch = (id & 7) ^ (row & 7);                                \
      __builtin_amdgcn_global_load_lds(                                            \
          (const __attribute__((address_space(1))) void*)(Aptr +                   \
              (size_t)(m0 + row) * 1024 + k0 + ch * 8),                            \
          (__attribute__((address_space(3))) void*)&Al[(it * 256 + w * 64) * 8],   \
          16, 0, 0);                                                               \
      __builtin_amdgcn_global_load_lds(                                            \
          (const __attribute__((address_space(1))) void*)(BTptr +                  \
              (size_t)(n0 + row) * 1024 + k0 + ch * 8),                            \
          (__attribute__((address_space(3))) void*)&Bl[(it * 256 + w * 64) * 8],   \
          16, 0, 0);                                                               \
    }                                                                              \
    __syncthreads();                                                               \
    _Pragma("unroll")                                                              \
    for (int ks = 0; ks < 2; ++ks) {                                               \
      bf16x8 a[4], bb[4];                                                          \
      _Pragma("unroll")                                                            \
      for (int i = 0; i < 4; ++i) {                                                \
        int ra = wm * 64 + i * 16 + lr;                                            \
        a[i] = *reinterpret_cast<const bf16x8*>(                                   \
            &Al[ra * 64 + (((ks * 4 + lg) ^ (ra & 7)) << 3)]);                     \
        int rb = wn * 64 + i * 16 + lr;                                            \
        bb[i] = *reinterpret_cast<const bf16x8*>(                                  \
            &Bl[rb * 64 + (((ks * 4 + lg) ^ (rb & 7)) << 3)]);                     \
      }                                                                            \
      _Pragma("unroll")                                                            \
      for (int mi = 0; mi < 4; ++mi)                                               \
        _Pragma("unroll")                                                          \
        for (int ni = 0; ni < 4; ++ni)                                             \
          acc[mi][ni] = MFMA(a[mi], bb[ni], acc[mi][ni]);                          \
    }                                                                              \
    __syncthreads();                                                               \
  }

// fused Q/K/V projections
__global__ __launch_bounds__(256) void proj_fused_kernel(
    const bf16* __restrict__ qb, const bf16* __restrict__ kvb,
    const bf16* __restrict__ wqT, const bf16* __restrict__ wkT,
    const bf16* __restrict__ wvT, bf16* __restrict__ Qp,
    bf16* __restrict__ Kp, bf16* __restrict__ VpT) {
  const int z = blockIdx.z;
  const bf16* Ain = (z == 0) ? qb : kvb;
  const bf16* BTin = (z == 0) ? wqT : (z == 1) ? wkT : wvT;
  GEMM_BODY(Ain, BTin)
  if (z < 2) {
    bf16* dst = (z == 0) ? Qp : Kp;
#pragma unroll
    for (int mi = 0; mi < 4; ++mi)
#pragma unroll
      for (int ni = 0; ni < 4; ++ni)
#pragma unroll
        for (int j = 0; j < 4; ++j) {
          int gm = m0 + wm * 64 + mi * 16 + 4 * lg + j;
          int gn = n0 + wn * 64 + ni * 16 + lr;
          dst[(((size_t)((gm >> 11) * 16 + (gn >> 6)) * 2048 + (gm & 2047)) << 6) +
              (gn & 63)] = (bf16)acc[mi][ni][j];
        }
  } else {
#pragma unroll
    for (int mi = 0; mi < 4; ++mi)
#pragma unroll
      for (int ni = 0; ni < 4; ++ni) {
        int gm0 = m0 + wm * 64 + mi * 16 + 4 * lg;
        int gn = n0 + wn * 64 + ni * 16 + lr;
        bf16x4 pv;
#pragma unroll
        for (int j = 0; j < 4; ++j) pv[j] = (bf16)acc[mi][ni][j];
        *reinterpret_cast<bf16x4*>(
            &VpT[((size_t)((gm0 >> 11) * 16 + (gn >> 6)) * 64 + (gn & 63)) * 2048 +
                 (gm0 & 2047)]) = pv;
      }
  }
}

// output GEMM
__global__ __launch_bounds__(256) void out_gemm_kernel(
    const bf16* __restrict__ preb, const bf16* __restrict__ woT,
    float* __restrict__ out) {
  GEMM_BODY(preb, woT)
#pragma unroll
  for (int mi = 0; mi < 4; ++mi)
#pragma unroll
    for (int ni = 0; ni < 4; ++ni)
#pragma unroll
      for (int j = 0; j < 4; ++j) {
        int gm = m0 + wm * 64 + mi * 16 + 4 * lg + j;
        int gn = n0 + wn * 64 + ni * 16 + lr;
        out[(size_t)gm * 1024 + gn] = acc[mi][ni][j];
      }
}

// ---------------- fused attention ----------------
// 1024 blocks x 256 thr; block = 64 q (4 waves x 16 q) of one bh; K/V LDS dbuf
// (32 KB exactly -> 5 blocks/CU). P never touches LDS: PV A-fragments built
// in-register via a 2-stage butterfly over the lg groups.
// Fixed-max softmax in exp2 units: p = exp2(s*0.125*log2e - 8*log2e).
__global__ __launch_bounds__(256) void attn_kernel(
    const bf16* __restrict__ Qp, const bf16* __restrict__ Kp,
    const bf16* __restrict__ VpT, bf16* __restrict__ preb) {
  __shared__ bf16 Klds[2][64 * 64];
  __shared__ bf16 Vlds[2][64 * 64];

  const int bh = blockIdx.y;
  const int b = bh >> 4, h = bh & 15;
  const int j = (blockIdx.x + blockIdx.y) & 31;  // q-tile, diagonal remap
  const int tid = threadIdx.x;
  const int w = tid >> 6;
  const int lane = tid & 63;
  const int lr = lane & 15, lg = lane >> 4;
  const int qb0 = j * 64 + w * 16;

  const bf16* Qb = Qp + (size_t)bh * NC * NK;
  const bf16* Kb = Kp + (size_t)bh * NC * NK;
  const bf16* Vb = VpT + (size_t)bh * NV * NC;

  bf16x8 qfr[2];
#pragma unroll
  for (int s = 0; s < 2; ++s)
    qfr[s] = *reinterpret_cast<const bf16x8*>(
        Qb + (size_t)(qb0 + lr) * NK + s * 32 + lg * 8);

  f32x4 acc[4] = {};
  float llane = 0.f;

  const float SC = 0.18033688f;     // 0.125 * log2(e)
  const float O_IN = -11.541560f;   // -8 * log2(e)
  const float O_MK = -29.575249f;   // (-12.5 - 8) * log2(e)

  // staging: per-thread rows r0, r1 with fixed swizzled chunk; ptrs advance
  const int srow = tid >> 3;        // 0..31  (= w*8 + lane>>3)
  const int sch0 = tid & 7;
  const int r0 = srow, r1 = 32 + srow;
  const int ch0 = sch0 ^ (r0 & 7), ch1 = sch0 ^ (r1 & 7);
  const bf16* k0p = Kb + (size_t)r0 * NK + ch0 * 8;
  const bf16* k1p = Kb + (size_t)r1 * NK + ch1 * 8;
  const bf16* v0p = Vb + (size_t)r0 * NC + ch0 * 8;
  const bf16* v1p = Vb + (size_t)r1 * NC + ch1 * 8;

  auto STAGE = [&](int buf) {
    __builtin_amdgcn_global_load_lds(
        (const __attribute__((address_space(1))) void*)k0p,
        (__attribute__((address_space(3))) void*)&Klds[buf][(w * 8) * 64], 16, 0, 0);
    __builtin_amdgcn_global_load_lds(
        (const __attribute__((address_space(1))) void*)k1p,
        (__attribute__((address_space(3))) void*)&Klds[buf][(32 + w * 8) * 64], 16, 0, 0);
    __builtin_amdgcn_global_load_lds(
        (const __attribute__((address_space(1))) void*)v0p,
        (__attribute__((address_space(3))) void*)&Vlds[buf][(w * 8) * 64], 16, 0, 0);
    __builtin_amdgcn_global_load_lds(
        (const __attribute__((address_space(1))) void*)v1p,
        (__attribute__((address_space(3))) void*)&Vlds[buf][(32 + w * 8) * 64], 16, 0, 0);
    k0p += 64 * NK; k1p += 64 * NK; v0p += 64; v1p += 64;
  };

  const int nt = (j == 0) ? (NC / 64) : (j + 1);

  STAGE(0);
  asm volatile("s_waitcnt vmcnt(0)" ::: "memory");
  __syncthreads();

  const bool xb = (lane & 32) != 0;
  const bool yb = (lane & 16) != 0;

  for (int t = 0; t < nt; ++t) {
    const int cur = t & 1;
    const int c0 = t * 64;
    if (t + 1 < nt) STAGE(cur ^ 1);

    const char* KL = (const char*)&Klds[cur][0];
    const char* VL = (const char*)&Vlds[cur][0];

    // ---- QK^T swapped: lane holds q = qb0+lr (col); keys c0+kf*16+4lg+i (rows)
    f32x4 S[4] = {};
#pragma unroll
    for (int s = 0; s < 2; ++s)
#pragma unroll
      for (int kf = 0; kf < 4; ++kf) {
        bf16x8 kfr = *reinterpret_cast<const bf16x8*>(
            KL + (kf * 16 + lr) * 128 + (((s * 4 + lg) ^ (lr & 7)) << 4));
        S[kf] = MFMA(kfr, qfr[s], S[kf]);
      }

    // ---- fixed-max softmax (exp2 units), lane-local l, P kept in registers
    bf16x4 pq[4];
    {
      const int qg = qb0 + lr;
      float lp[4];
      if (t < j) {
#pragma unroll
        for (int kf = 0; kf < 4; ++kf) {
          float s0 = exp2f(fmaf(S[kf][0], SC, O_IN));
          float s1 = exp2f(fmaf(S[kf][1], SC, O_IN));
          float s2 = exp2f(fmaf(S[kf][2], SC, O_IN));
          float s3 = exp2f(fmaf(S[kf][3], SC, O_IN));
          pq[kf][0] = (bf16)s0; pq[kf][1] = (bf16)s1;
          pq[kf][2] = (bf16)s2; pq[kf][3] = (bf16)s3;
          lp[kf] = (s0 + s1) + (s2 + s3);
        }
      } else if (t == j) {
#pragma unroll
        for (int kf = 0; kf < 4; ++kf) {
          float sv[4];
#pragma unroll
          for (int i = 0; i < 4; ++i) {
            int key = c0 + kf * 16 + 4 * lg + i;
            sv[i] = exp2f(fmaf(S[kf][i], SC, (key > qg) ? O_MK : O_IN));
            pq[kf][i] = (bf16)sv[i];
          }
          lp[kf] = (sv[0] + sv[1]) + (sv[2] + sv[3]);
        }
      } else {  // fully-masked tile (only j==0 blocks)
#pragma unroll
        for (int kf = 0; kf < 4; ++kf) {
          float sv[4];
#pragma unroll
          for (int i = 0; i < 4; ++i) {
            sv[i] = exp2f(fmaf(S[kf][i], SC, O_MK));
            pq[kf][i] = (bf16)sv[i];
          }
          lp[kf] = (sv[0] + sv[1]) + (sv[2] + sv[3]);
        }
      }
      llane += (lp[0] + lp[1]) + (lp[2] + lp[3]);
    }

    // ---- build PV A-fragments in-register (2-stage lg-butterfly) ----
    // lane(lr,lg) holds keys kf*16+4lg+{0..3}; needs keys s2*32+8lg+{0..7}.
    bf16x8 pa[2];
#pragma unroll
    for (int s2 = 0; s2 < 2; ++s2) {
      uint2 V0 = __builtin_bit_cast(uint2, pq[2 * s2]);
      uint2 V1 = __builtin_bit_cast(uint2, pq[2 * s2 + 1]);
      unsigned a0 = V0.x, a1 = V0.y, b0 = V1.x, b1 = V1.y;
      // stage 1: swap lane-bit5 with reg-slot bit
      unsigned t0 = xb ? a0 : b0, t1 = xb ? a1 : b1;
      unsigned e0 = (unsigned)__shfl_xor((int)t0, 32);
      unsigned e1 = (unsigned)__shfl_xor((int)t1, 32);
      unsigned A0 = xb ? e0 : a0, A1 = xb ? e1 : a1;
      unsigned B0 = xb ? b0 : e0, B1 = xb ? b1 : e1;
      // stage 2: swap lane-bit4 with reg-slot bit
      unsigned u0 = yb ? A0 : B0, u1 = yb ? A1 : B1;
      unsigned f0 = (unsigned)__shfl_xor((int)u0, 16);
      unsigned f1 = (unsigned)__shfl_xor((int)u1, 16);
      unsigned nA0 = yb ? f0 : A0, nA1 = yb ? f1 : A1;
      unsigned nB0 = yb ? B0 : f0, nB1 = yb ? B1 : f1;
      uint4 r{nA0, nA1, nB0, nB1};
      pa[s2] = __builtin_bit_cast(bf16x8, r);
    }

    // ---- PV: acc[q][v] += P[q][keys] * V^T[v][keys]
#pragma unroll
    for (int s2 = 0; s2 < 2; ++s2)
#pragma unroll
      for (int vf = 0; vf < 4; ++vf) {
        bf16x8 vfr = *reinterpret_cast<const bf16x8*>(
            VL + (vf * 16 + lr) * 128 + (((s2 * 4 + lg) ^ (lr & 7)) << 4));
        acc[vf] = MFMA(pa[s2], vfr, acc[vf]);
      }

    asm volatile("s_waitcnt vmcnt(0)" ::: "memory");  // prefetch landed
    __syncthreads();                                   // safe to swap buffers
  }

  // ---- epilogue: reduce l over lg replicas, normalize, store
  llane += __shfl_xor(llane, 16);
  llane += __shfl_xor(llane, 32);
  float li[4];
#pragma unroll
  for (int i = 0; i < 4; ++i) li[i] = 1.0f / __shfl(llane, 4 * lg + i);
  bf16* ob = preb + ((size_t)b * NC) * NHV + (size_t)h * NV;
#pragma unroll
  for (int vf = 0; vf < 4; ++vf)
#pragma unroll
    for (int i = 0; i < 4; ++i) {
      int d = qb0 + 4 * lg + i;
      ob[(size_t)d * NHV + vf * 16 + lr] = (bf16)(acc[vf][i] * li[i]);
    }
}

// ---------------- launch ----------------

extern "C" void kernel_launch(void* const* d_in, const int* in_sizes, int n_in,
                              void* d_out, int out_size, void* d_ws, size_t ws_size,
                              hipStream_t stream) {
  const float* kvinput = (const float*)d_in[0];
  const float* qinput  = (const float*)d_in[1];
  const float* wq = (const float*)d_in[2];
  const float* wk = (const float*)d_in[3];
  const float* wv = (const float*)d_in[4];
  const float* wo = (const float*)d_in[5];
  float* out = (float*)d_out;

  char* ws = (char*)d_ws;
  bf16* qb   = (bf16*)(ws + 0);          //  8,388,608  [NB][NC][NM]
  bf16* kvb  = (bf16*)(ws + 8388608);    //  8,388,608
  bf16* wqT  = (bf16*)(ws + 16777216);   //  2,097,152  [NH][64][NM]
  bf16* wkT  = (bf16*)(ws + 18874368);   //  2,097,152
  bf16* wvT  = (bf16*)(ws + 20971520);   //  2,097,152
  bf16* woT  = (bf16*)(ws + 23068672);   //  2,097,152  [NM][NHV]
  bf16* Qp   = (bf16*)(ws + 25165824);   //  8,388,608  [NB*NH][NC][64]
  bf16* Kp   = (bf16*)(ws + 33554432);   //  8,388,608
  bf16* VpT  = (bf16*)(ws + 41943040);   //  8,388,608  [NB*NH][64][NC]
  bf16* preb = (bf16*)(ws + 50331648);   //  8,388,608  [NB][NC][NHV]

  prep_kernel<<<5120, 256, 0, stream>>>(qinput, kvinput, wq, wk, wv, wo,
                                        qb, kvb, wqT, wkT, wvT, woT);

  dim3 pg(32, 8, 3);  // M/128, N/128, {Q,K,V}
  proj_fused_kernel<<<pg, 256, 0, stream>>>(qb, kvb, wqT, wkT, wvT, Qp, Kp, VpT);

  dim3 ag(32, NB * NH);  // 32 q-tiles x 32 bh
  attn_kernel<<<ag, 256, 0, stream>>>(Qp, Kp, VpT, preb);

  dim3 og(32, 8);
  out_gemm_kernel<<<og, 256, 0, stream>>>(preb, woT, out);
}